// Round 5
// baseline (197.302 us; speedup 1.0000x reference)
//
#include <hip/hip_runtime.h>
#include <hip/hip_bf16.h>

typedef __attribute__((ext_vector_type(8))) short bf16x8;
typedef __attribute__((ext_vector_type(4))) float f32x4;
typedef unsigned short u16;

__device__ __forceinline__ u16 f2bf(float f) {
  unsigned u = __float_as_uint(f);
  u += 0x7fffu + ((u >> 16) & 1u);
  return (u16)(u >> 16);
}

__device__ __forceinline__ void gload16(const void* g, void* l) {
  __builtin_amdgcn_global_load_lds(
      (const __attribute__((address_space(1))) unsigned int*)g,
      (__attribute__((address_space(3))) unsigned int*)l, 16, 0, 0);
}

// raw workgroup barrier WITHOUT implicit vmcnt(0) drain
__device__ __forceinline__ void blockbar() {
  asm volatile("" ::: "memory");
  __builtin_amdgcn_s_barrier();
  asm volatile("" ::: "memory");
}

// ---------------- merged prep: tobf16 x3, wtrans x4, rope tables -----------
__global__ __launch_bounds__(256) void prep_kernel(
    const float* __restrict__ query, const float* __restrict__ key_,
    const float* __restrict__ value, u16* __restrict__ qin,
    u16* __restrict__ kin, u16* __restrict__ vin,
    const float* __restrict__ Wq, const float* __restrict__ Wk,
    const float* __restrict__ Wv, const float* __restrict__ Wo,
    u16* __restrict__ WqT, u16* __restrict__ WkT, u16* __restrict__ WvT,
    u16* __restrict__ WoT, float* __restrict__ cosT, float* __restrict__ sinT) {
  __shared__ float tile[32][33];
  const int z = blockIdx.z;
  const int bx = blockIdx.x;
  const int tid = threadIdx.x;
  if (z < 3) {
    const float* in = z == 0 ? query : z == 1 ? key_ : value;
    u16* out = z == 0 ? qin : z == 1 ? kin : vin;
    size_t i = ((size_t)bx * 256 + tid) * 4;
    float4 v = *(const float4*)(in + i);
    ushort4 o = make_ushort4(f2bf(v.x), f2bf(v.y), f2bf(v.z), f2bf(v.w));
    *(ushort4*)(out + i) = o;
  } else if (z == 3) {
    const int w = bx >> 10;
    const float* W = w == 0 ? Wq : w == 1 ? Wk : w == 2 ? Wv : Wo;
    u16* Wt = w == 0 ? WqT : w == 1 ? WkT : w == 2 ? WvT : WoT;
    int tx = tid & 31, ty = tid >> 5;
    int k0 = ((bx >> 5) & 31) * 32, n0 = (bx & 31) * 32;
#pragma unroll
    for (int i = 0; i < 4; ++i)
      tile[ty + i * 8][tx] = W[(size_t)(k0 + ty + i * 8) * 1024 + n0 + tx];
    __syncthreads();
#pragma unroll
    for (int i = 0; i < 4; ++i)
      Wt[(size_t)(n0 + ty + i * 8) * 1024 + k0 + tx] = f2bf(tile[tx][ty + i * 8]);
  } else {
    int i = bx * 256 + tid;
    if (i >= 1024 * 32) return;
    int s = i >> 5, p = i & 31;
    double freq = exp(-9.210340371976184 * (double)(2 * p) / 64.0);
    double ang = sin((double)s * freq);
    cosT[i] = (float)cos(ang);
    sinT[i] = (float)sin(ang);
  }
}

// ---------------- merged Q/K/V projection GEMM (dbuf, counted vmcnt) -------
__global__ __launch_bounds__(256) void proj_gemm_kernel(
    const u16* __restrict__ qin, const u16* __restrict__ kin,
    const u16* __restrict__ vin, const u16* __restrict__ WqT,
    const u16* __restrict__ WkT, const u16* __restrict__ WvT,
    const float* __restrict__ bq, const float* __restrict__ bk,
    const float* __restrict__ bv, u16* __restrict__ qr, u16* __restrict__ kr,
    u16* __restrict__ vt, const float* __restrict__ cosT,
    const float* __restrict__ sinT) {
  __shared__ u16 lA[2][128 * 32];
  __shared__ u16 lB[2][128 * 32];
  const int z = blockIdx.z;
  const u16* A = z == 0 ? qin : z == 1 ? kin : vin;
  const u16* Bt = z == 0 ? WqT : z == 1 ? WkT : WvT;
  const float* bias = z == 0 ? bq : z == 1 ? bk : bv;

  const int tid = threadIdx.x;
  const int lane = tid & 63, wid = tid >> 6;
  const int wm = wid >> 1, wn = wid & 1;
  const int lr = lane & 15, kg = lane >> 4;
  const int m0 = blockIdx.y * 128, n0 = blockIdx.x * 128;

  auto stage = [&](int bu, int k0) {
#pragma unroll
    for (int it = 0; it < 2; ++it) {
      int o = tid * 16 + it * 4096;
      int row = o >> 6;
      int cbs = (((o >> 4) & 3) ^ (row & 3)) << 4;
      gload16((const char*)A + ((size_t)(m0 + row) * 1024 + k0) * 2 + cbs,
              (char*)lA[bu] + o);
      gload16((const char*)Bt + ((size_t)(n0 + row) * 1024 + k0) * 2 + cbs,
              (char*)lB[bu] + o);
    }
  };

  stage(0, 0);
  f32x4 acc[4][4] = {};
  for (int t = 0; t < 32; ++t) {
    if (t < 31) {
      stage((t + 1) & 1, (t + 1) * 32);
      asm volatile("s_waitcnt vmcnt(4)" ::: "memory");
    } else {
      asm volatile("s_waitcnt vmcnt(0)" ::: "memory");
    }
    blockbar();
    const int cb = t & 1;
    bf16x8 av[4], bv_[4];
#pragma unroll
    for (int i = 0; i < 4; ++i) {
      int ra = wm * 64 + i * 16 + lr;
      av[i] = *(const bf16x8*)((const char*)lA[cb] + ra * 64 + ((kg ^ (ra & 3)) << 4));
      int rb = wn * 64 + i * 16 + lr;
      bv_[i] = *(const bf16x8*)((const char*)lB[cb] + rb * 64 + ((kg ^ (rb & 3)) << 4));
    }
#pragma unroll
    for (int i = 0; i < 4; ++i)
#pragma unroll
      for (int j = 0; j < 4; ++j)
        acc[i][j] = __builtin_amdgcn_mfma_f32_16x16x32_bf16(av[i], bv_[j], acc[i][j], 0, 0, 0);
    blockbar();
  }

  if (z == 2) {
    const int bb = m0 >> 10;
#pragma unroll
    for (int i = 0; i < 4; ++i) {
      int srow = (m0 & 1023) + wm * 64 + i * 16 + kg * 4;
#pragma unroll
      for (int j = 0; j < 4; ++j) {
        int col = n0 + wn * 64 + j * 16 + lr;
        float bcol = bias[col];
        int h = col >> 6, d = col & 63;
        ushort4 o;
        o.x = f2bf(acc[i][j][0] + bcol);
        o.y = f2bf(acc[i][j][1] + bcol);
        o.z = f2bf(acc[i][j][2] + bcol);
        o.w = f2bf(acc[i][j][3] + bcol);
        *(ushort4*)(vt + ((size_t)((bb * 16 + h) * 64 + d)) * 1024 + srow) = o;
      }
    }
  } else {
    u16* Cout = z == 0 ? qr : kr;
#pragma unroll
    for (int i = 0; i < 4; ++i) {
#pragma unroll
      for (int j = 0; j < 4; ++j) {
        int col = n0 + wn * 64 + j * 16 + lr;
        float bcol = bias[col];
#pragma unroll
        for (int r = 0; r < 4; ++r) {
          int row = m0 + wm * 64 + i * 16 + kg * 4 + r;
          float v = acc[i][j][r] + bcol;
          float pv = __shfl_xor(v, 1);
          int p = (col & 63) >> 1;
          int s = row & 1023;
          float ct = cosT[s * 32 + p], st = sinT[s * 32 + p];
          float ov = (col & 1) ? (v * ct + pv * st) : (v * ct - pv * st);
          Cout[(size_t)row * 1024 + col] = f2bf(ov);
        }
      }
    }
  }
}

// ---------------- final output GEMM (dbuf, counted vmcnt), f32 out ---------
__global__ __launch_bounds__(256) void out_gemm_kernel(
    const u16* __restrict__ A, const u16* __restrict__ Bt,
    const float* __restrict__ bias, float* __restrict__ Cout) {
  __shared__ u16 lA[2][128 * 32];
  __shared__ u16 lB[2][128 * 32];
  const int tid = threadIdx.x;
  const int lane = tid & 63, wid = tid >> 6;
  const int wm = wid >> 1, wn = wid & 1;
  const int lr = lane & 15, kg = lane >> 4;
  const int m0 = blockIdx.y * 128, n0 = blockIdx.x * 128;

  auto stage = [&](int bu, int k0) {
#pragma unroll
    for (int it = 0; it < 2; ++it) {
      int o = tid * 16 + it * 4096;
      int row = o >> 6;
      int cbs = (((o >> 4) & 3) ^ (row & 3)) << 4;
      gload16((const char*)A + ((size_t)(m0 + row) * 1024 + k0) * 2 + cbs,
              (char*)lA[bu] + o);
      gload16((const char*)Bt + ((size_t)(n0 + row) * 1024 + k0) * 2 + cbs,
              (char*)lB[bu] + o);
    }
  };

  stage(0, 0);
  f32x4 acc[4][4] = {};
  for (int t = 0; t < 32; ++t) {
    if (t < 31) {
      stage((t + 1) & 1, (t + 1) * 32);
      asm volatile("s_waitcnt vmcnt(4)" ::: "memory");
    } else {
      asm volatile("s_waitcnt vmcnt(0)" ::: "memory");
    }
    blockbar();
    const int cb = t & 1;
    bf16x8 av[4], bv_[4];
#pragma unroll
    for (int i = 0; i < 4; ++i) {
      int ra = wm * 64 + i * 16 + lr;
      av[i] = *(const bf16x8*)((const char*)lA[cb] + ra * 64 + ((kg ^ (ra & 3)) << 4));
      int rb = wn * 64 + i * 16 + lr;
      bv_[i] = *(const bf16x8*)((const char*)lB[cb] + rb * 64 + ((kg ^ (rb & 3)) << 4));
    }
#pragma unroll
    for (int i = 0; i < 4; ++i)
#pragma unroll
      for (int j = 0; j < 4; ++j)
        acc[i][j] = __builtin_amdgcn_mfma_f32_16x16x32_bf16(av[i], bv_[j], acc[i][j], 0, 0, 0);
    blockbar();
  }
#pragma unroll
  for (int i = 0; i < 4; ++i)
#pragma unroll
    for (int j = 0; j < 4; ++j) {
      int col = n0 + wn * 64 + j * 16 + lr;
      float bcol = bias[col];
#pragma unroll
      for (int r = 0; r < 4; ++r) {
        int row = m0 + wm * 64 + i * 16 + kg * 4 + r;
        Cout[(size_t)row * 1024 + col] = acc[i][j][r] + bcol;
      }
    }
}

// ---------------- fused scores + softmax + PV (two-pass, S^T swapped) ------
// Block: 256 threads (4 waves), 32 q-rows of one (b,h). Occupancy: 4 blk/CU.
// Pass 1: rsum[q] = sum_k exp(s/8) over 8x128-k chunks (S discarded).
// Pass 2: 16x64-k chunks: recompute S (bitwise identical), p = exp(s/8)*inv,
//         float4 probs store + ushort4 lP store, PV accumulate.
// mfma(K, Q) => S^T fragments: lane holds q = ii*16+lr, k = base+kg*4+r
// (4 consecutive k per reg quad -> vectorized stores).
__global__ __launch_bounds__(256, 4) void fused_attn_kernel(
    const u16* __restrict__ qr, const u16* __restrict__ kr,
    const u16* __restrict__ vt, float* __restrict__ probs,
    u16* __restrict__ ctx) {
  __shared__ u16 big[2][8192];  // pass1: K 128x64; pass2: K 64x64 | V 64x64
  __shared__ u16 lP[32 * 64];
  __shared__ float redS[4][32];

  const int tid = threadIdx.x;
  const int lane = tid & 63, wid = tid >> 6;
  const int lr = lane & 15, kg = lane >> 4;
  const int z = blockIdx.y, b = z >> 4, h = z & 15;
  const int m0 = blockIdx.x * 32;

  const char* Qb = (const char*)qr + ((size_t)(b * 1024 + m0) * 1024 + h * 64) * 2;
  const char* Kb = (const char*)kr + ((size_t)(b * 1024) * 1024 + h * 64) * 2;
  const char* Vb = (const char*)vt + (size_t)z * 64 * 1024 * 2;

  // Q fragments straight to registers (b-frag: col=lr -> q, 8 d at kg*8)
  bf16x8 qf[2][2];
#pragma unroll
  for (int ii = 0; ii < 2; ++ii)
#pragma unroll
    for (int ks = 0; ks < 2; ++ks)
      qf[ii][ks] =
          *(const bf16x8*)(Qb + (size_t)(ii * 16 + lr) * 2048 + (ks * 4 + kg) * 16);

  auto stage1 = [&](int bu, int c) {  // K chunk of 128 rows x 128B
#pragma unroll
    for (int it = 0; it < 4; ++it) {
      int o = tid * 16 + it * 4096;
      int row = o >> 7, ch = (o >> 4) & 7;
      gload16(Kb + (size_t)(c * 128 + row) * 2048 + ((ch ^ (row & 7)) << 4),
              (char*)big[bu] + o);
    }
  };
  auto stage2 = [&](int bu, int c2) {  // K 64x128B | V 64x128B
#pragma unroll
    for (int it = 0; it < 2; ++it) {
      int o = tid * 16 + it * 4096;
      int row = o >> 7, ch = (o >> 4) & 7;
      gload16(Kb + (size_t)(c2 * 64 + row) * 2048 + ((ch ^ (row & 7)) << 4),
              (char*)big[bu] + o);
    }
#pragma unroll
    for (int it = 0; it < 2; ++it) {
      int o = tid * 16 + it * 4096;
      int row = o >> 7, ch = (o >> 4) & 7;
      gload16(Vb + (size_t)row * 2048 + c2 * 128 + ((ch ^ (row & 7)) << 4),
              (char*)big[bu] + 8192 + o);
    }
  };

  // ---- pass 1: row sums of exp(s/8) ----
  float rsum[2] = {0.f, 0.f};
  stage1(0, 0);
#pragma unroll 2
  for (int c = 0; c < 8; ++c) {
    if (c < 7) {
      stage1((c + 1) & 1, c + 1);
      asm volatile("s_waitcnt vmcnt(4)" ::: "memory");
    } else {
      asm volatile("s_waitcnt vmcnt(0)" ::: "memory");
    }
    blockbar();
    const char* KB = (const char*)big[c & 1];
    f32x4 aS[2][2] = {};
#pragma unroll
    for (int ks = 0; ks < 2; ++ks) {
      bf16x8 kf[2];
#pragma unroll
      for (int jj = 0; jj < 2; ++jj) {
        int rb = wid * 32 + jj * 16 + lr;
        kf[jj] = *(const bf16x8*)(KB + rb * 128 + (((ks * 4 + kg) ^ (rb & 7)) << 4));
      }
#pragma unroll
      for (int ii = 0; ii < 2; ++ii)
#pragma unroll
        for (int jj = 0; jj < 2; ++jj)
          aS[ii][jj] =
              __builtin_amdgcn_mfma_f32_16x16x32_bf16(kf[jj], qf[ii][ks], aS[ii][jj], 0, 0, 0);
    }
#pragma unroll
    for (int ii = 0; ii < 2; ++ii)
#pragma unroll
      for (int jj = 0; jj < 2; ++jj)
#pragma unroll
        for (int r = 0; r < 4; ++r)
          rsum[ii] += __expf(aS[ii][jj][r] * 0.125f);
    blockbar();
  }

  // prefetch pass-2 chunk 0 (big[0] free: last read at pass-1 c==6)
  stage2(0, 0);

  // reduce: kg groups (lanes ^16, ^32) then cross-wave via LDS
#pragma unroll
  for (int ii = 0; ii < 2; ++ii) {
    float v = rsum[ii];
    v += __shfl_xor(v, 16);
    v += __shfl_xor(v, 32);
    rsum[ii] = v;
  }
  if (lane < 16) {
    redS[wid][lane] = rsum[0];
    redS[wid][16 + lane] = rsum[1];
  }
  asm volatile("s_waitcnt vmcnt(0) lgkmcnt(0)" ::: "memory");
  blockbar();
  float inv[2];
#pragma unroll
  for (int ii = 0; ii < 2; ++ii) {
    int row = ii * 16 + lr;
    inv[ii] = 1.0f / (redS[0][row] + redS[1][row] + redS[2][row] + redS[3][row]);
  }

  // ---- pass 2: probs + PV ----
  const int ipv = wid >> 1, jpv = wid & 1;
  f32x4 accPV[2] = {};
  float* Pg = probs + (size_t)z * 1024 * 1024 + (size_t)m0 * 1024;

#pragma unroll 2
  for (int c2 = 0; c2 < 16; ++c2) {
    const int cur = c2 & 1;
    if (c2 < 15) stage2(cur ^ 1, c2 + 1);
    const char* KB = (const char*)big[cur];
    // recompute S^T chunk (bitwise identical to pass 1)
    f32x4 aS2[2] = {};
#pragma unroll
    for (int ks = 0; ks < 2; ++ks) {
      int rb = wid * 16 + lr;
      bf16x8 kf = *(const bf16x8*)(KB + rb * 128 + (((ks * 4 + kg) ^ (rb & 7)) << 4));
#pragma unroll
      for (int ii = 0; ii < 2; ++ii)
        aS2[ii] = __builtin_amdgcn_mfma_f32_16x16x32_bf16(kf, qf[ii][ks], aS2[ii], 0, 0, 0);
    }
#pragma unroll
    for (int ii = 0; ii < 2; ++ii) {
      float4 p4;
      p4.x = __expf(aS2[ii][0] * 0.125f) * inv[ii];
      p4.y = __expf(aS2[ii][1] * 0.125f) * inv[ii];
      p4.z = __expf(aS2[ii][2] * 0.125f) * inv[ii];
      p4.w = __expf(aS2[ii][3] * 0.125f) * inv[ii];
      int row = ii * 16 + lr;
      *(float4*)(Pg + (size_t)row * 1024 + c2 * 64 + wid * 16 + kg * 4) = p4;
      int bytecol = (wid * 16 + kg * 4) * 2;
      int ch = bytecol >> 4, sub = bytecol & 15;
      ushort4 pb = make_ushort4(f2bf(p4.x), f2bf(p4.y), f2bf(p4.z), f2bf(p4.w));
      *(ushort4*)((char*)lP + row * 128 + ((ch ^ (row & 7)) << 4) + sub) = pb;
    }
    asm volatile("s_waitcnt lgkmcnt(0)" ::: "memory");
    blockbar();
    const char* VB = (const char*)big[cur] + 8192;
#pragma unroll
    for (int ks = 0; ks < 2; ++ks) {
      int ra = ipv * 16 + lr;
      bf16x8 pa =
          *(const bf16x8*)((const char*)lP + ra * 128 + (((ks * 4 + kg) ^ (ra & 7)) << 4));
#pragma unroll
      for (int jjj = 0; jjj < 2; ++jjj) {
        int rb = jpv * 32 + jjj * 16 + lr;
        bf16x8 vbf = *(const bf16x8*)(VB + rb * 128 + (((ks * 4 + kg) ^ (rb & 7)) << 4));
        accPV[jjj] = __builtin_amdgcn_mfma_f32_16x16x32_bf16(pa, vbf, accPV[jjj], 0, 0, 0);
      }
    }
    if (c2 < 15) asm volatile("s_waitcnt vmcnt(2)" ::: "memory");
    blockbar();
  }

#pragma unroll
  for (int jjj = 0; jjj < 2; ++jjj)
#pragma unroll
    for (int r = 0; r < 4; ++r) {
      int row = m0 + ipv * 16 + kg * 4 + r;
      int d = jpv * 32 + jjj * 16 + lr;
      ctx[((size_t)(b * 1024 + row)) * 1024 + h * 64 + d] = f2bf(accPV[jjj][r]);
    }
}

// ---------------------------------------------------------------------------
extern "C" void kernel_launch(void* const* d_in, const int* in_sizes, int n_in,
                              void* d_out, int out_size, void* d_ws, size_t ws_size,
                              hipStream_t stream) {
  const float* query = (const float*)d_in[0];
  const float* key_ = (const float*)d_in[1];
  const float* value = (const float*)d_in[2];
  const float* Wq = (const float*)d_in[3];
  const float* bq = (const float*)d_in[4];
  const float* Wk = (const float*)d_in[5];
  const float* bk = (const float*)d_in[6];
  const float* Wv = (const float*)d_in[7];
  const float* bv = (const float*)d_in[8];
  const float* Wo = (const float*)d_in[9];
  const float* bo = (const float*)d_in[10];

  float* out = (float*)d_out;
  float* probs = out + (size_t)4 * 1024 * 1024;

  char* w = (char*)d_ws;
  const size_t SZ_MK = (size_t)4096 * 1024 * 2;  // 8 MB bf16
  const size_t SZ_W = (size_t)1024 * 1024 * 2;   // 2 MB bf16
  u16* qin = (u16*)w; w += SZ_MK;
  u16* kin = (u16*)w; w += SZ_MK;
  u16* vin = (u16*)w; w += SZ_MK;
  u16* qr = (u16*)w; w += SZ_MK;
  u16* kr = (u16*)w; w += SZ_MK;
  u16* vt = (u16*)w; w += SZ_MK;   // (b,h,d,s) written directly by proj z==2
  u16* WqT = (u16*)w; w += SZ_W;
  u16* WkT = (u16*)w; w += SZ_W;
  u16* WvT = (u16*)w; w += SZ_W;
  u16* WoT = (u16*)w; w += SZ_W;
  float* cosT = (float*)w; w += 1024 * 32 * 4;
  float* sinT = (float*)w; w += 1024 * 32 * 4;
  u16* ctx = qin;  // qin dead after q-projection; ctx written by fused attn

  dim3 blk(256);
  hipLaunchKernelGGL(prep_kernel, dim3(4096, 1, 5), blk, 0, stream,
                     query, key_, value, qin, kin, vin, Wq, Wk, Wv, Wo,
                     WqT, WkT, WvT, WoT, cosT, sinT);
  hipLaunchKernelGGL(proj_gemm_kernel, dim3(8, 32, 3), blk, 0, stream,
                     qin, kin, vin, WqT, WkT, WvT, bq, bk, bv, qr, kr, vt,
                     cosT, sinT);
  hipLaunchKernelGGL(fused_attn_kernel, dim3(32, 64), blk, 0, stream,
                     qr, kr, vt, probs, ctx);
  hipLaunchKernelGGL(out_gemm_kernel, dim3(8, 32), blk, 0, stream,
                     ctx, WoT, bo, out);
}

// Round 6
// 192.570 us; speedup vs baseline: 1.0246x; 1.0246x over previous
//
#include <hip/hip_runtime.h>
#include <hip/hip_bf16.h>

typedef __attribute__((ext_vector_type(8))) short bf16x8;
typedef __attribute__((ext_vector_type(4))) float f32x4;
typedef unsigned short u16;

__device__ __forceinline__ u16 f2bf(float f) {
  unsigned u = __float_as_uint(f);
  u += 0x7fffu + ((u >> 16) & 1u);
  return (u16)(u >> 16);
}

__device__ __forceinline__ void gload16(const void* g, void* l) {
  __builtin_amdgcn_global_load_lds(
      (const __attribute__((address_space(1))) unsigned int*)g,
      (__attribute__((address_space(3))) unsigned int*)l, 16, 0, 0);
}

// raw workgroup barrier WITHOUT implicit vmcnt(0) drain
__device__ __forceinline__ void blockbar() {
  asm volatile("" ::: "memory");
  __builtin_amdgcn_s_barrier();
  asm volatile("" ::: "memory");
}

// ---------------- merged prep: tobf16 x3, wtrans x4, rope tables -----------
__global__ __launch_bounds__(256) void prep_kernel(
    const float* __restrict__ query, const float* __restrict__ key_,
    const float* __restrict__ value, u16* __restrict__ qin,
    u16* __restrict__ kin, u16* __restrict__ vin,
    const float* __restrict__ Wq, const float* __restrict__ Wk,
    const float* __restrict__ Wv, const float* __restrict__ Wo,
    u16* __restrict__ WqT, u16* __restrict__ WkT, u16* __restrict__ WvT,
    u16* __restrict__ WoT, float* __restrict__ cosT, float* __restrict__ sinT) {
  __shared__ float tile[32][33];
  const int z = blockIdx.z;
  const int bx = blockIdx.x;
  const int tid = threadIdx.x;
  if (z < 3) {
    const float* in = z == 0 ? query : z == 1 ? key_ : value;
    u16* out = z == 0 ? qin : z == 1 ? kin : vin;
    size_t i = ((size_t)bx * 256 + tid) * 4;
    float4 v = *(const float4*)(in + i);
    ushort4 o = make_ushort4(f2bf(v.x), f2bf(v.y), f2bf(v.z), f2bf(v.w));
    *(ushort4*)(out + i) = o;
  } else if (z == 3) {
    const int w = bx >> 10;
    const float* W = w == 0 ? Wq : w == 1 ? Wk : w == 2 ? Wv : Wo;
    u16* Wt = w == 0 ? WqT : w == 1 ? WkT : w == 2 ? WvT : WoT;
    int tx = tid & 31, ty = tid >> 5;
    int k0 = ((bx >> 5) & 31) * 32, n0 = (bx & 31) * 32;
#pragma unroll
    for (int i = 0; i < 4; ++i)
      tile[ty + i * 8][tx] = W[(size_t)(k0 + ty + i * 8) * 1024 + n0 + tx];
    __syncthreads();
#pragma unroll
    for (int i = 0; i < 4; ++i)
      Wt[(size_t)(n0 + ty + i * 8) * 1024 + k0 + tx] = f2bf(tile[tx][ty + i * 8]);
  } else {
    int i = bx * 256 + tid;
    if (i >= 1024 * 32) return;
    int s = i >> 5, p = i & 31;
    double freq = exp(-9.210340371976184 * (double)(2 * p) / 64.0);
    double ang = sin((double)s * freq);
    cosT[i] = (float)cos(ang);
    sinT[i] = (float)sin(ang);
  }
}

// ---------------- merged Q/K/V projection GEMM (dbuf, counted vmcnt) -------
__global__ __launch_bounds__(256) void proj_gemm_kernel(
    const u16* __restrict__ qin, const u16* __restrict__ kin,
    const u16* __restrict__ vin, const u16* __restrict__ WqT,
    const u16* __restrict__ WkT, const u16* __restrict__ WvT,
    const float* __restrict__ bq, const float* __restrict__ bk,
    const float* __restrict__ bv, u16* __restrict__ qr, u16* __restrict__ kr,
    u16* __restrict__ vt, const float* __restrict__ cosT,
    const float* __restrict__ sinT) {
  __shared__ u16 lA[2][128 * 32];
  __shared__ u16 lB[2][128 * 32];
  const int z = blockIdx.z;
  const u16* A = z == 0 ? qin : z == 1 ? kin : vin;
  const u16* Bt = z == 0 ? WqT : z == 1 ? WkT : WvT;
  const float* bias = z == 0 ? bq : z == 1 ? bk : bv;

  const int tid = threadIdx.x;
  const int lane = tid & 63, wid = tid >> 6;
  const int wm = wid >> 1, wn = wid & 1;
  const int lr = lane & 15, kg = lane >> 4;
  const int m0 = blockIdx.y * 128, n0 = blockIdx.x * 128;

  auto stage = [&](int bu, int k0) {
#pragma unroll
    for (int it = 0; it < 2; ++it) {
      int o = tid * 16 + it * 4096;
      int row = o >> 6;
      int cbs = (((o >> 4) & 3) ^ (row & 3)) << 4;
      gload16((const char*)A + ((size_t)(m0 + row) * 1024 + k0) * 2 + cbs,
              (char*)lA[bu] + o);
      gload16((const char*)Bt + ((size_t)(n0 + row) * 1024 + k0) * 2 + cbs,
              (char*)lB[bu] + o);
    }
  };

  stage(0, 0);
  f32x4 acc[4][4] = {};
  for (int t = 0; t < 32; ++t) {
    if (t < 31) {
      stage((t + 1) & 1, (t + 1) * 32);
      asm volatile("s_waitcnt vmcnt(4)" ::: "memory");
    } else {
      asm volatile("s_waitcnt vmcnt(0)" ::: "memory");
    }
    blockbar();
    const int cb = t & 1;
    bf16x8 av[4], bv_[4];
#pragma unroll
    for (int i = 0; i < 4; ++i) {
      int ra = wm * 64 + i * 16 + lr;
      av[i] = *(const bf16x8*)((const char*)lA[cb] + ra * 64 + ((kg ^ (ra & 3)) << 4));
      int rb = wn * 64 + i * 16 + lr;
      bv_[i] = *(const bf16x8*)((const char*)lB[cb] + rb * 64 + ((kg ^ (rb & 3)) << 4));
    }
#pragma unroll
    for (int i = 0; i < 4; ++i)
#pragma unroll
      for (int j = 0; j < 4; ++j)
        acc[i][j] = __builtin_amdgcn_mfma_f32_16x16x32_bf16(av[i], bv_[j], acc[i][j], 0, 0, 0);
    blockbar();
  }

  if (z == 2) {
    const int bb = m0 >> 10;
#pragma unroll
    for (int i = 0; i < 4; ++i) {
      int srow = (m0 & 1023) + wm * 64 + i * 16 + kg * 4;
#pragma unroll
      for (int j = 0; j < 4; ++j) {
        int col = n0 + wn * 64 + j * 16 + lr;
        float bcol = bias[col];
        int h = col >> 6, d = col & 63;
        ushort4 o;
        o.x = f2bf(acc[i][j][0] + bcol);
        o.y = f2bf(acc[i][j][1] + bcol);
        o.z = f2bf(acc[i][j][2] + bcol);
        o.w = f2bf(acc[i][j][3] + bcol);
        *(ushort4*)(vt + ((size_t)((bb * 16 + h) * 64 + d)) * 1024 + srow) = o;
      }
    }
  } else {
    u16* Cout = z == 0 ? qr : kr;
#pragma unroll
    for (int i = 0; i < 4; ++i) {
#pragma unroll
      for (int j = 0; j < 4; ++j) {
        int col = n0 + wn * 64 + j * 16 + lr;
        float bcol = bias[col];
#pragma unroll
        for (int r = 0; r < 4; ++r) {
          int row = m0 + wm * 64 + i * 16 + kg * 4 + r;
          float v = acc[i][j][r] + bcol;
          float pv = __shfl_xor(v, 1);
          int p = (col & 63) >> 1;
          int s = row & 1023;
          float ct = cosT[s * 32 + p], st = sinT[s * 32 + p];
          float ov = (col & 1) ? (v * ct + pv * st) : (v * ct - pv * st);
          Cout[(size_t)row * 1024 + col] = f2bf(ov);
        }
      }
    }
  }
}

// ---------------- final output GEMM (dbuf, counted vmcnt), f32 out ---------
__global__ __launch_bounds__(256) void out_gemm_kernel(
    const u16* __restrict__ A, const u16* __restrict__ Bt,
    const float* __restrict__ bias, float* __restrict__ Cout) {
  __shared__ u16 lA[2][128 * 32];
  __shared__ u16 lB[2][128 * 32];
  const int tid = threadIdx.x;
  const int lane = tid & 63, wid = tid >> 6;
  const int wm = wid >> 1, wn = wid & 1;
  const int lr = lane & 15, kg = lane >> 4;
  const int m0 = blockIdx.y * 128, n0 = blockIdx.x * 128;

  auto stage = [&](int bu, int k0) {
#pragma unroll
    for (int it = 0; it < 2; ++it) {
      int o = tid * 16 + it * 4096;
      int row = o >> 6;
      int cbs = (((o >> 4) & 3) ^ (row & 3)) << 4;
      gload16((const char*)A + ((size_t)(m0 + row) * 1024 + k0) * 2 + cbs,
              (char*)lA[bu] + o);
      gload16((const char*)Bt + ((size_t)(n0 + row) * 1024 + k0) * 2 + cbs,
              (char*)lB[bu] + o);
    }
  };

  stage(0, 0);
  f32x4 acc[4][4] = {};
  for (int t = 0; t < 32; ++t) {
    if (t < 31) {
      stage((t + 1) & 1, (t + 1) * 32);
      asm volatile("s_waitcnt vmcnt(4)" ::: "memory");
    } else {
      asm volatile("s_waitcnt vmcnt(0)" ::: "memory");
    }
    blockbar();
    const int cb = t & 1;
    bf16x8 av[4], bv_[4];
#pragma unroll
    for (int i = 0; i < 4; ++i) {
      int ra = wm * 64 + i * 16 + lr;
      av[i] = *(const bf16x8*)((const char*)lA[cb] + ra * 64 + ((kg ^ (ra & 3)) << 4));
      int rb = wn * 64 + i * 16 + lr;
      bv_[i] = *(const bf16x8*)((const char*)lB[cb] + rb * 64 + ((kg ^ (rb & 3)) << 4));
    }
#pragma unroll
    for (int i = 0; i < 4; ++i)
#pragma unroll
      for (int j = 0; j < 4; ++j)
        acc[i][j] = __builtin_amdgcn_mfma_f32_16x16x32_bf16(av[i], bv_[j], acc[i][j], 0, 0, 0);
    blockbar();
  }
#pragma unroll
  for (int i = 0; i < 4; ++i)
#pragma unroll
    for (int j = 0; j < 4; ++j) {
      int col = n0 + wn * 64 + j * 16 + lr;
      float bcol = bias[col];
#pragma unroll
      for (int r = 0; r < 4; ++r) {
        int row = m0 + wm * 64 + i * 16 + kg * 4 + r;
        Cout[(size_t)row * 1024 + col] = acc[i][j][r] + bcol;
      }
    }
}

// ---------------- fused scores + softmax + PV (single-pass, 8 waves) -------
// Block: 512 threads (8 waves), 32 q-rows of one (b,h).
// Phase 1: wave w owns k-cols [w*16, w*16+16) of each 128-k chunk:
//          accS[8][2] (64 regs). Phase 2: row softmax (shfl + 8-wave LDS
//          combine). Phase 3: wave w = (q-half ipv, d-quarter jpv): 16q x 16d.
__global__ __launch_bounds__(512, 4) void fused_attn_kernel(
    const u16* __restrict__ qr, const u16* __restrict__ kr,
    const u16* __restrict__ vt, float* __restrict__ probs,
    u16* __restrict__ ctx) {
  __shared__ u16 lQ[32 * 64];
  __shared__ u16 lK[2][128 * 64];
  __shared__ u16 lV[2][64 * 128];
  __shared__ u16 lP[32 * 128];
  __shared__ float redM[8][32];
  __shared__ float redS[8][32];

  const int tid = threadIdx.x;
  const int lane = tid & 63, wid = tid >> 6;  // wid in [0,8)
  const int lr = lane & 15, kg = lane >> 4;
  const int z = blockIdx.y, b = z >> 4, h = z & 15;
  const int m0 = blockIdx.x * 32;

  const char* Qb = (const char*)qr + ((size_t)(b * 1024 + m0) * 1024 + h * 64) * 2;
  const char* Kb = (const char*)kr + ((size_t)(b * 1024) * 1024 + h * 64) * 2;
  const char* Vb = (const char*)vt + (size_t)z * 64 * 1024 * 2;

  auto stageK = [&](int bu, int c) {  // 128 rows x 128 B = 16 KB, 2 loads/thr
#pragma unroll
    for (int it = 0; it < 2; ++it) {
      int o = tid * 16 + it * 8192;
      int row = o >> 7, ch = (o >> 4) & 7;
      gload16(Kb + (size_t)(c * 128 + row) * 2048 + ((ch ^ (row & 7)) << 4),
              (char*)lK[bu] + o);
    }
  };
  auto stageV = [&](int bu, int c) {  // 64 rows x 256 B = 16 KB, 2 loads/thr
#pragma unroll
    for (int it = 0; it < 2; ++it) {
      int o = tid * 16 + it * 8192;
      int row = o >> 8, ch = (o >> 4) & 15;
      gload16(Vb + (size_t)row * 2048 + c * 256 + ((ch ^ (row & 15)) << 4),
              (char*)lV[bu] + o);
    }
  };

  // prologue: stage Q (first 256 threads) + K chunk 0
  if (tid < 256) {
    int o = tid * 16;
    int row = o >> 7, ch = (o >> 4) & 7;
    gload16(Qb + (size_t)row * 2048 + ((ch ^ (row & 7)) << 4), (char*)lQ + o);
  }
  stageK(0, 0);

  bf16x8 qf[2][2];
  f32x4 accS[8][2] = {};
#pragma unroll
  for (int c = 0; c < 8; ++c) {
    if (c < 7) {
      stageK((c + 1) & 1, c + 1);
      asm volatile("s_waitcnt vmcnt(2)" ::: "memory");
    } else {
      asm volatile("s_waitcnt vmcnt(0)" ::: "memory");
    }
    blockbar();
    if (c == 0) {
#pragma unroll
      for (int ii = 0; ii < 2; ++ii)
#pragma unroll
        for (int ks = 0; ks < 2; ++ks) {
          int ra = ii * 16 + lr;
          int cc = ks * 4 + kg;
          qf[ii][ks] = *(const bf16x8*)((const char*)lQ + ra * 128 + ((cc ^ (ra & 7)) << 4));
        }
    }
#pragma unroll
    for (int ks = 0; ks < 2; ++ks) {
      int rb = wid * 16 + lr;
      bf16x8 kf =
          *(const bf16x8*)((const char*)lK[c & 1] + rb * 128 + (((ks * 4 + kg) ^ (rb & 7)) << 4));
#pragma unroll
      for (int ii = 0; ii < 2; ++ii)
        accS[c][ii] =
            __builtin_amdgcn_mfma_f32_16x16x32_bf16(qf[ii][ks], kf, accS[c][ii], 0, 0, 0);
    }
    blockbar();
  }

  // prefetch V chunk 0; stays in flight through lgkm-only barriers below
  stageV(0, 0);

  // ---- softmax ----
  float rmax[2][4];
#pragma unroll
  for (int ii = 0; ii < 2; ++ii)
#pragma unroll
    for (int r = 0; r < 4; ++r) rmax[ii][r] = -1e30f;
#pragma unroll
  for (int c = 0; c < 8; ++c)
#pragma unroll
    for (int ii = 0; ii < 2; ++ii)
#pragma unroll
      for (int r = 0; r < 4; ++r) {
        float v = accS[c][ii][r] * 0.125f;
        accS[c][ii][r] = v;
        rmax[ii][r] = fmaxf(rmax[ii][r], v);
      }
#pragma unroll
  for (int ii = 0; ii < 2; ++ii)
#pragma unroll
    for (int r = 0; r < 4; ++r) {
      float v = rmax[ii][r];
      v = fmaxf(v, __shfl_xor(v, 1));
      v = fmaxf(v, __shfl_xor(v, 2));
      v = fmaxf(v, __shfl_xor(v, 4));
      v = fmaxf(v, __shfl_xor(v, 8));
      rmax[ii][r] = v;
    }
  if (lr == 0) {
#pragma unroll
    for (int ii = 0; ii < 2; ++ii)
#pragma unroll
      for (int r = 0; r < 4; ++r) redM[wid][ii * 16 + kg * 4 + r] = rmax[ii][r];
  }
  asm volatile("s_waitcnt lgkmcnt(0)" ::: "memory");
  blockbar();
  float rowm[2][4], rsum[2][4];
#pragma unroll
  for (int ii = 0; ii < 2; ++ii)
#pragma unroll
    for (int r = 0; r < 4; ++r) {
      int row = ii * 16 + kg * 4 + r;
      float m01 = fmaxf(redM[0][row], redM[1][row]);
      float m23 = fmaxf(redM[2][row], redM[3][row]);
      float m45 = fmaxf(redM[4][row], redM[5][row]);
      float m67 = fmaxf(redM[6][row], redM[7][row]);
      rowm[ii][r] = fmaxf(fmaxf(m01, m23), fmaxf(m45, m67));
      rsum[ii][r] = 0.f;
    }
#pragma unroll
  for (int c = 0; c < 8; ++c)
#pragma unroll
    for (int ii = 0; ii < 2; ++ii)
#pragma unroll
      for (int r = 0; r < 4; ++r) {
        float e = __expf(accS[c][ii][r] - rowm[ii][r]);
        accS[c][ii][r] = e;
        rsum[ii][r] += e;
      }
#pragma unroll
  for (int ii = 0; ii < 2; ++ii)
#pragma unroll
    for (int r = 0; r < 4; ++r) {
      float v = rsum[ii][r];
      v += __shfl_xor(v, 1);
      v += __shfl_xor(v, 2);
      v += __shfl_xor(v, 4);
      v += __shfl_xor(v, 8);
      rsum[ii][r] = v;
    }
  if (lr == 0) {
#pragma unroll
    for (int ii = 0; ii < 2; ++ii)
#pragma unroll
      for (int r = 0; r < 4; ++r) redS[wid][ii * 16 + kg * 4 + r] = rsum[ii][r];
  }
  asm volatile("s_waitcnt lgkmcnt(0)" ::: "memory");
  blockbar();
  float inv[2][4];
#pragma unroll
  for (int ii = 0; ii < 2; ++ii)
#pragma unroll
    for (int r = 0; r < 4; ++r) {
      int row = ii * 16 + kg * 4 + r;
      float s = redS[0][row] + redS[1][row] + redS[2][row] + redS[3][row] +
                redS[4][row] + redS[5][row] + redS[6][row] + redS[7][row];
      inv[ii][r] = 1.0f / s;
    }

  // ---- phase 3: probs write + PV ----
  const int ipv = wid >> 2, jpv = wid & 3;  // 16q-half, 16d-quarter
  f32x4 accPV = {};
  float* Pg = probs + (size_t)z * 1024 * 1024 + (size_t)m0 * 1024;

#pragma unroll
  for (int c = 0; c < 8; ++c) {
    if (c < 7) stageV((c + 1) & 1, c + 1);
#pragma unroll
    for (int ii = 0; ii < 2; ++ii)
#pragma unroll
      for (int r = 0; r < 4; ++r) {
        float p = accS[c][ii][r] * inv[ii][r];
        int row = ii * 16 + kg * 4 + r;
        int col = wid * 16 + lr;
        Pg[(size_t)row * 1024 + c * 128 + col] = p;
        *(u16*)((char*)lP + row * 256 + ((((col >> 3) ^ (row & 15))) << 4) + (col & 7) * 2) =
            f2bf(p);
      }
    // newest per wave: 8 probs-store insts (+2 V loads if staged) -> leave
    // those outstanding, require prior-chunk V loads + older ops done.
    if (c < 7)
      asm volatile("s_waitcnt vmcnt(10) lgkmcnt(0)" ::: "memory");
    else
      asm volatile("s_waitcnt vmcnt(8) lgkmcnt(0)" ::: "memory");
    blockbar();
#pragma unroll
    for (int ks = 0; ks < 4; ++ks) {
      int cc = ks * 4 + kg;
      int ra = ipv * 16 + lr;
      bf16x8 pa = *(const bf16x8*)((const char*)lP + ra * 256 + ((cc ^ (ra & 15)) << 4));
      int rb = jpv * 16 + lr;
      bf16x8 vbf = *(const bf16x8*)((const char*)lV[c & 1] + rb * 256 + ((cc ^ (rb & 15)) << 4));
      accPV = __builtin_amdgcn_mfma_f32_16x16x32_bf16(pa, vbf, accPV, 0, 0, 0);
    }
    blockbar();
  }

#pragma unroll
  for (int r = 0; r < 4; ++r) {
    int row = m0 + ipv * 16 + kg * 4 + r;
    int d = jpv * 16 + lr;
    ctx[((size_t)(b * 1024 + row)) * 1024 + h * 64 + d] = f2bf(accPV[r]);
  }
}

// ---------------------------------------------------------------------------
extern "C" void kernel_launch(void* const* d_in, const int* in_sizes, int n_in,
                              void* d_out, int out_size, void* d_ws, size_t ws_size,
                              hipStream_t stream) {
  const float* query = (const float*)d_in[0];
  const float* key_ = (const float*)d_in[1];
  const float* value = (const float*)d_in[2];
  const float* Wq = (const float*)d_in[3];
  const float* bq = (const float*)d_in[4];
  const float* Wk = (const float*)d_in[5];
  const float* bk = (const float*)d_in[6];
  const float* Wv = (const float*)d_in[7];
  const float* bv = (const float*)d_in[8];
  const float* Wo = (const float*)d_in[9];
  const float* bo = (const float*)d_in[10];

  float* out = (float*)d_out;
  float* probs = out + (size_t)4 * 1024 * 1024;

  char* w = (char*)d_ws;
  const size_t SZ_MK = (size_t)4096 * 1024 * 2;  // 8 MB bf16
  const size_t SZ_W = (size_t)1024 * 1024 * 2;   // 2 MB bf16
  u16* qin = (u16*)w; w += SZ_MK;
  u16* kin = (u16*)w; w += SZ_MK;
  u16* vin = (u16*)w; w += SZ_MK;
  u16* qr = (u16*)w; w += SZ_MK;
  u16* kr = (u16*)w; w += SZ_MK;
  u16* vt = (u16*)w; w += SZ_MK;   // (b,h,d,s) written directly by proj z==2
  u16* WqT = (u16*)w; w += SZ_W;
  u16* WkT = (u16*)w; w += SZ_W;
  u16* WvT = (u16*)w; w += SZ_W;
  u16* WoT = (u16*)w; w += SZ_W;
  float* cosT = (float*)w; w += 1024 * 32 * 4;
  float* sinT = (float*)w; w += 1024 * 32 * 4;
  u16* ctx = qin;  // qin dead after q-projection; ctx written by fused attn

  dim3 blk(256);
  hipLaunchKernelGGL(prep_kernel, dim3(4096, 1, 5), blk, 0, stream,
                     query, key_, value, qin, kin, vin, Wq, Wk, Wv, Wo,
                     WqT, WkT, WvT, WoT, cosT, sinT);
  hipLaunchKernelGGL(proj_gemm_kernel, dim3(8, 32, 3), blk, 0, stream,
                     qin, kin, vin, WqT, WkT, WvT, bq, bk, bv, qr, kr, vt,
                     cosT, sinT);
  hipLaunchKernelGGL(fused_attn_kernel, dim3(32, 64), dim3(512), 0, stream,
                     qr, kr, vt, probs, ctx);
  hipLaunchKernelGGL(out_gemm_kernel, dim3(8, 32), blk, 0, stream,
                     ctx, WoT, bo, out);
}